// Round 5
// baseline (422.035 us; speedup 1.0000x reference)
//
#include <hip/hip_runtime.h>
#include <math.h>

#define DIM 512
#define HEADS 8
#define QL 225
#define VS 196
#define BATCH 4
#define EPS_BN 1e-5f

typedef __attribute__((ext_vector_type(8))) short bf16x8;
typedef __attribute__((ext_vector_type(4))) float f32x4;

// ---------------- wave (64-lane) reductions ----------------
__device__ __forceinline__ float waveMax(float v) {
#pragma unroll
    for (int o = 32; o; o >>= 1) v = fmaxf(v, __shfl_xor(v, o, 64));
    return v;
}
__device__ __forceinline__ float waveSum(float v) {
#pragma unroll
    for (int o = 32; o; o >>= 1) v += __shfl_xor(v, o, 64);
    return v;
}

// ---------------- fp32 -> bf16 pack helpers ----------------
__device__ __forceinline__ unsigned cvt_pk_bf16(float lo, float hi) {
    unsigned r;
    asm("v_cvt_pk_bf16_f32 %0, %1, %2" : "=v"(r) : "v"(lo), "v"(hi));
    return r;
}
__device__ __forceinline__ uint4 ld_cvt8(const float* p) {
    float4 x = *(const float4*)p;
    float4 y = *(const float4*)(p + 4);
    uint4 r;
    r.x = cvt_pk_bf16(x.x, x.y);
    r.y = cvt_pk_bf16(x.z, x.w);
    r.z = cvt_pk_bf16(y.x, y.y);
    r.w = cvt_pk_bf16(y.z, y.w);
    return r;
}

// ---------------- multi-job bf16-MFMA GEMM (N=K=512): Out = scale*A@W^T (+bias)(relu)(+Add) ----
// A,W are fp32 in memory; converted to bf16 while staging to LDS; fp32 accumulate.
// Tile: 128x128, BK=32, 4 waves (2x2), each wave 64x64 = 4x4 frags of 16x16x32.
struct GJob {
    const float* A; const float* W; const float* bias; const float* Add; float* Out;
    long aBS, aOff, addBS, addOff;
    int aRows, addRows, M, relu;
    float scale; int pad0, pad1, pad2;
};
struct GJobs { GJob j[4]; };

__global__ __launch_bounds__(256) void gemm_multi(GJobs jobs) {
    const GJob J = jobs.j[blockIdx.z];
    const int bm = blockIdx.y * 128, bn = blockIdx.x * 128;
    if (bm >= J.M) return;
    // row padded 32 -> 40 shorts (80 B): 16-row frag reads are 2-way conflict (free)
    __shared__ __align__(16) ushort As[128][40];
    __shared__ __align__(16) ushort Bs[128][40];
    const int tid = threadIdx.x;

    // staging: units u in {tid, tid+256}; row = u>>2, kq = u&3 (8 consecutive k each)
    const int arow0 = tid >> 2, akq = tid & 3;
    const int arow1 = arow0 + 64;
    const float *ap0 = nullptr, *ap1 = nullptr;
    {
        int m0 = bm + arow0;
        if (m0 < J.M) { int bb = m0 / J.aRows; int r = m0 - bb * J.aRows;
                        ap0 = J.A + bb * J.aBS + J.aOff + (long)r * 512 + akq * 8; }
        int m1 = bm + arow1;
        if (m1 < J.M) { int bb = m1 / J.aRows; int r = m1 - bb * J.aRows;
                        ap1 = J.A + bb * J.aBS + J.aOff + (long)r * 512 + akq * 8; }
    }
    const float* bp0 = J.W + (long)(bn + arow0) * 512 + akq * 8;
    const float* bp1 = J.W + (long)(bn + arow1) * 512 + akq * 8;

    const int lane = tid & 63, wid = tid >> 6;
    const int wr = wid >> 1, wc = wid & 1;       // 2x2 wave grid
    const int lr = lane & 15, kg = lane >> 4;    // frag row/col + k-group

    f32x4 acc[4][4] = {};

    for (int kt = 0; kt < 512; kt += 32) {
        const uint4 z = {0u, 0u, 0u, 0u};
        uint4 va0 = ap0 ? ld_cvt8(ap0 + kt) : z;
        uint4 va1 = ap1 ? ld_cvt8(ap1 + kt) : z;
        uint4 vb0 = ld_cvt8(bp0 + kt);
        uint4 vb1 = ld_cvt8(bp1 + kt);
        __syncthreads();  // previous iteration's frag reads done
        *(uint4*)&As[arow0][akq * 8] = va0;
        *(uint4*)&As[arow1][akq * 8] = va1;
        *(uint4*)&Bs[arow0][akq * 8] = vb0;
        *(uint4*)&Bs[arow1][akq * 8] = vb1;
        __syncthreads();  // tile visible
        bf16x8 a[4], b[4];
#pragma unroll
        for (int i = 0; i < 4; i++) a[i] = *(const bf16x8*)&As[wr * 64 + i * 16 + lr][kg * 8];
#pragma unroll
        for (int j = 0; j < 4; j++) b[j] = *(const bf16x8*)&Bs[wc * 64 + j * 16 + lr][kg * 8];
#pragma unroll
        for (int i = 0; i < 4; i++)
#pragma unroll
            for (int j = 0; j < 4; j++)
                acc[i][j] = __builtin_amdgcn_mfma_f32_16x16x32_bf16(a[i], b[j], acc[i][j], 0, 0, 0);
    }

    // epilogue: C/D layout col = lane&15, row = (lane>>4)*4 + reg
#pragma unroll
    for (int i = 0; i < 4; i++) {
#pragma unroll
        for (int r = 0; r < 4; r++) {
            int m = bm + wr * 64 + i * 16 + kg * 4 + r;
            if (m >= J.M) continue;
            const float* addrow = nullptr;
            if (J.Add) {
                int bb = m / J.addRows; int rr = m - bb * J.addRows;
                addrow = J.Add + bb * J.addBS + J.addOff + (long)rr * 512;
            }
            float* orow = J.Out + (long)m * 512;
#pragma unroll
            for (int j = 0; j < 4; j++) {
                int n = bn + wc * 64 + j * 16 + lr;
                float v = acc[i][j][r] * J.scale;
                if (J.bias) v += J.bias[n];
                if (J.relu) v = fmaxf(v, 0.f);
                if (addrow) v += addrow[n];
                orow[n] = v;
            }
        }
    }
}

// ---------------- attention 1: P[b,h,n,q] = softmax_n( q[b,q,:]·k[b,n,:] ) (transposed store) ----
__global__ __launch_bounds__(256) void attn1_kernel(const float* __restrict__ qs,
                                                    const float* __restrict__ ks,
                                                    float* __restrict__ P) {
    int bid = blockIdx.x;
    int qi = bid % QL;
    int h = (bid / QL) % HEADS;
    int b = bid / (QL * HEADS);
    __shared__ float qrow[64];
    __shared__ float redm[4], reds[4];
    int tid = threadIdx.x;
    if (tid < 64) qrow[tid] = qs[((long)(b * QL + qi)) * DIM + h * 64 + tid];
    __syncthreads();
    float s = -1e30f;
    if (tid < VS) {
        const float* kr = ks + ((long)(b * VS + tid)) * DIM + h * 64;
        float acc = 0.f;
#pragma unroll 16
        for (int d = 0; d < 64; d++) acc += qrow[d] * kr[d];
        s = acc;
    }
    float wm = waveMax(s);
    if ((tid & 63) == 0) redm[tid >> 6] = wm;
    __syncthreads();
    float m = fmaxf(fmaxf(redm[0], redm[1]), fmaxf(redm[2], redm[3]));
    float e = (tid < VS) ? expf(s - m) : 0.f;
    float ws = waveSum(e);
    if ((tid & 63) == 0) reds[tid >> 6] = ws;
    __syncthreads();
    float tot = reds[0] + reds[1] + reds[2] + reds[3];
    if (tid < VS) P[(((long)(b * HEADS + h)) * VS + tid) * QL + qi] = e / tot;
}

// ---------------- fused: h = P*v -> dwconv1+bn1+relu -> dwconv2+bn2+relu -> mean over n ----
#define CSTEP(N, HAm,HAc,HAp, HBm,HBc,HBp, HCm,HCc,HCp, GAm,GAc,GAp, GBm,GBc,GBp, GCm,GCc,GCp) \
{                                                                                             \
    float pv = 0.f;                                                                           \
    if ((N) < VS) {                                                                           \
        float vn = vcol[(N)];                                                                 \
        if (qload) pv = Pp[(long)(N) * QL + q] * vn;                                          \
    }                                                                                         \
    HCc = pv;                                                                                 \
    HCm = __shfl_up(pv, 1, 64);                                                               \
    HCp = __shfl_down(pv, 1, 64);                                                             \
    float g = 0.f;                                                                            \
    if (gok && (N) >= 1 && (N) <= VS) {                                                       \
        float a1 = w1s[0]*HAm + w1s[1]*HAc + w1s[2]*HAp                                       \
                 + w1s[3]*HBm + w1s[4]*HBc + w1s[5]*HBp                                       \
                 + w1s[6]*HCm + w1s[7]*HCc + w1s[8]*HCp;                                      \
        g = fmaxf(a1 * s1 + b1v, 0.f);                                                        \
    }                                                                                         \
    GCc = g;                                                                                  \
    GCm = __shfl_up(g, 1, 64);                                                                \
    GCp = __shfl_down(g, 1, 64);                                                              \
    if ((N) >= 2) {                                                                           \
        float a2 = w2s[0]*GAm + w2s[1]*GAc + w2s[2]*GAp                                       \
                 + w2s[3]*GBm + w2s[4]*GBc + w2s[5]*GBp                                       \
                 + w2s[6]*GCm + w2s[7]*GCc + w2s[8]*GCp;                                      \
        csum += fmaxf(a2 * s2 + b2v, 0.f);                                                    \
    }                                                                                         \
}

__global__ __launch_bounds__(256) void conv_fuse_kernel(
    const float* __restrict__ P, const float* __restrict__ vs,
    const float* __restrict__ dw1, const float* __restrict__ dw2,
    const float* __restrict__ bn1g, const float* __restrict__ bn1b,
    const float* __restrict__ bn1m, const float* __restrict__ bn1v,
    const float* __restrict__ bn2g, const float* __restrict__ bn2b,
    const float* __restrict__ bn2m, const float* __restrict__ bn2v,
    float* __restrict__ m2) {
    int bc = blockIdx.x;
    int c = bc & (DIM - 1);
    int b = bc >> 9;
    int h = c >> 6;
    int tid = threadIdx.x;
    int wave = tid >> 6, lane = tid & 63;
    int q = wave * 60 + lane - 2;
    bool qload = (q >= 0 && q < QL);
    bool gok = (lane >= 1 && lane <= 62 && q >= 0 && q < QL);
    bool outok = (lane >= 2 && lane <= 61 && q < QL);
    __shared__ float vcol[VS];
    if (tid < VS) vcol[tid] = vs[((long)(b * VS + tid)) * DIM + c];
    float w1s[9], w2s[9];
#pragma unroll
    for (int i = 0; i < 9; i++) { w1s[i] = dw1[c * 9 + i]; w2s[i] = dw2[c * 9 + i]; }
    float s1 = bn1g[c] * rsqrtf(bn1v[c] + EPS_BN);
    float b1v = bn1b[c] - bn1m[c] * s1;
    float s2 = bn2g[c] * rsqrtf(bn2v[c] + EPS_BN);
    float b2v = bn2b[c] - bn2m[c] * s2;
    const float* Pp = P + ((long)(b * HEADS + h)) * VS * QL;
    __syncthreads();
    float HAm = 0, HAc = 0, HAp = 0, HBm = 0, HBc = 0, HBp = 0, HCm = 0, HCc = 0, HCp = 0;
    float GAm = 0, GAc = 0, GAp = 0, GBm = 0, GBc = 0, GBp = 0, GCm = 0, GCc = 0, GCp = 0;
    float csum = 0.f;
    for (int nb = 0; nb < 198; nb += 3) {
        CSTEP(nb,     HAm,HAc,HAp, HBm,HBc,HBp, HCm,HCc,HCp, GAm,GAc,GAp, GBm,GBc,GBp, GCm,GCc,GCp)
        CSTEP(nb + 1, HBm,HBc,HBp, HCm,HCc,HCp, HAm,HAc,HAp, GBm,GBc,GBp, GCm,GCc,GCp, GAm,GAc,GAp)
        CSTEP(nb + 2, HCm,HCc,HCp, HAm,HAc,HAp, HBm,HBc,HBp, GCm,GCc,GCp, GAm,GAc,GAp, GBm,GBc,GBp)
    }
    if (outok) m2[((long)(b * QL + q)) * DIM + c] = csum * (1.f / (float)VS);
}

// ---------------- attention 2: O[b,n,:] = Qm[b,n,:] + softmax_q(Qm·Km/sqrt(512)) @ Vm ----
__global__ __launch_bounds__(256) void attn2_kernel(const float* __restrict__ Qm,
                                                    const float* __restrict__ Km,
                                                    const float* __restrict__ Vm,
                                                    float* __restrict__ O) {
    int bid = blockIdx.x;
    int n = bid % VS;
    int h = (bid / VS) % HEADS;
    int b = bid / (VS * HEADS);
    __shared__ float qrow[64];
    __shared__ float av[QL];
    __shared__ float red[256];
    __shared__ float redm[4], reds[4];
    int tid = threadIdx.x;
    if (tid < 64) qrow[tid] = Qm[((long)(b * VS + n)) * DIM + h * 64 + tid];
    __syncthreads();
    float s = -1e30f;
    if (tid < QL) {
        const float* kr = Km + ((long)(b * QL + tid)) * DIM + h * 64;
        float acc = 0.f;
#pragma unroll 16
        for (int d = 0; d < 64; d++) acc += qrow[d] * kr[d];
        s = acc * 0.044194173824159216f; // 1/sqrt(512)
    }
    float wm = waveMax(s);
    if ((tid & 63) == 0) redm[tid >> 6] = wm;
    __syncthreads();
    float m = fmaxf(fmaxf(redm[0], redm[1]), fmaxf(redm[2], redm[3]));
    float e = (tid < QL) ? expf(s - m) : 0.f;
    float ws = waveSum(e);
    if ((tid & 63) == 0) reds[tid >> 6] = ws;
    __syncthreads();
    float tot = reds[0] + reds[1] + reds[2] + reds[3];
    if (tid < QL) av[tid] = e / tot;
    __syncthreads();
    int d = tid & 63, qp = tid >> 6;
    float acc = 0.f;
    for (int qq = qp; qq < QL; qq += 4) acc += av[qq] * Vm[((long)(b * QL + qq)) * DIM + h * 64 + d];
    red[tid] = acc;
    __syncthreads();
    if (tid < 64) {
        float r = red[tid] + red[tid + 64] + red[tid + 128] + red[tid + 192];
        O[((long)(b * VS + n)) * DIM + h * 64 + tid] = qrow[tid] + r;
    }
}

static inline GJob mkjob(const float* A, int aRows, long aBS, long aOff,
                         const float* W, const float* bias,
                         const float* Add, int addRows, long addBS, long addOff,
                         float* Out, int M, float scale, int relu) {
    GJob j;
    j.A = A; j.W = W; j.bias = bias; j.Add = Add; j.Out = Out;
    j.aBS = aBS; j.aOff = aOff; j.addBS = addBS; j.addOff = addOff;
    j.aRows = aRows; j.addRows = addRows; j.M = M; j.relu = relu;
    j.scale = scale; j.pad0 = j.pad1 = j.pad2 = 0;
    return j;
}

extern "C" void kernel_launch(void* const* d_in, const int* in_sizes, int n_in,
                              void* d_out, int out_size, void* d_ws, size_t ws_size,
                              hipStream_t stream) {
    const float* x     = (const float*)d_in[0];
    const float* Wq    = (const float*)d_in[1];
    const float* Wk    = (const float*)d_in[2];
    const float* Wv    = (const float*)d_in[3];
    const float* Wproj = (const float*)d_in[4];
    const float* bproj = (const float*)d_in[5];
    const float* dw1   = (const float*)d_in[6];
    const float* dw2   = (const float*)d_in[7];
    const float* pw    = (const float*)d_in[8];
    const float* bn1g  = (const float*)d_in[9];
    const float* bn1b  = (const float*)d_in[10];
    const float* bn1m  = (const float*)d_in[11];
    const float* bn1v  = (const float*)d_in[12];
    const float* bn2g  = (const float*)d_in[13];
    const float* bn2b  = (const float*)d_in[14];
    const float* bn2m  = (const float*)d_in[15];
    const float* bn2v  = (const float*)d_in[16];
    const float* mWq   = (const float*)d_in[17];
    const float* mbq   = (const float*)d_in[18];
    const float* mWk   = (const float*)d_in[19];
    const float* mbk   = (const float*)d_in[20];
    const float* mWv   = (const float*)d_in[21];
    const float* mbv   = (const float*)d_in[22];
    const float* mWo   = (const float*)d_in[23];
    const float* mbo   = (const float*)d_in[24];

    float* ws = (float*)d_ws;
    // Overlay (floats):
    //   qs @ 0 (460800) -> m2 -> Km
    //   ks @ 460800 (401408) -> O
    //   vsb @ 862208 (401408) -> O2
    //   P @ 1263616 (1411200) -> [kc @ +0 | Qm @ +460800 | Vm @ +862208]
    float* qs = ws;
    float* ks = ws + 460800;
    float* vsb = ws + 862208;
    float* P  = ws + 1263616;
    float* m2 = ws;
    float* kc = ws + 1263616;
    float* Qm = ws + 1263616 + 460800;
    float* Vm = ws + 1263616 + 460800 + 401408;
    float* Km = ws;
    float* O  = ws + 460800;
    float* O2 = ws + 862208;

    const long xBS = 421L * DIM;
    const long clsOff = 196L * DIM;

    dim3 blk(256);

    // L1: q,k,v projections fused
    {
        GJobs js;
        js.j[0] = mkjob(x, QL, xBS, clsOff, Wq, nullptr, nullptr, 1, 0, 0, qs, 900, 0.125f, 0);
        js.j[1] = mkjob(x, VS, xBS, 0, Wk, nullptr, nullptr, 1, 0, 0, ks, 784, 1.f, 0);
        js.j[2] = mkjob(x, VS, xBS, 0, Wv, nullptr, nullptr, 1, 0, 0, vsb, 784, 1.f, 0);
        js.j[3] = js.j[0];
        gemm_multi<<<dim3(4, 8, 3), blk, 0, stream>>>(js);
    }
    attn1_kernel<<<BATCH * HEADS * QL, blk, 0, stream>>>(qs, ks, P);
    conv_fuse_kernel<<<BATCH * DIM, blk, 0, stream>>>(P, vsb, dw1, dw2,
                                                      bn1g, bn1b, bn1m, bn1v,
                                                      bn2g, bn2b, bn2m, bn2v, m2);
    // L2: kc = cls_cat + m2 @ pw^T  AND  Qm = x_sem @ mWq^T + mbq   (P dead now)
    {
        GJobs js;
        js.j[0] = mkjob(m2, 900, 0, 0, pw, nullptr, x, QL, xBS, clsOff, kc, 900, 1.f, 0);
        js.j[1] = mkjob(x, VS, xBS, 0, mWq, mbq, nullptr, 1, 0, 0, Qm, 784, 1.f, 0);
        js.j[2] = js.j[3] = js.j[0];
        gemm_multi<<<dim3(4, 8, 2), blk, 0, stream>>>(js);
    }
    // L3: Km, Vm off kc
    {
        GJobs js;
        js.j[0] = mkjob(kc, 900, 0, 0, mWk, mbk, nullptr, 1, 0, 0, Km, 900, 1.f, 0);
        js.j[1] = mkjob(kc, 900, 0, 0, mWv, mbv, nullptr, 1, 0, 0, Vm, 900, 1.f, 0);
        js.j[2] = js.j[3] = js.j[0];
        gemm_multi<<<dim3(4, 8, 2), blk, 0, stream>>>(js);
    }
    attn2_kernel<<<BATCH * HEADS * VS, blk, 0, stream>>>(Qm, Km, Vm, O);
    // L4: O2 = O + relu(O @ mWo^T + mbo)
    {
        GJobs js;
        js.j[0] = mkjob(O, 784, 0, 0, mWo, mbo, O, 784, 0, 0, O2, 784, 1.f, 1);
        js.j[1] = js.j[2] = js.j[3] = js.j[0];
        gemm_multi<<<dim3(4, 7, 1), blk, 0, stream>>>(js);
    }
    // L5: out = O2 @ Wproj^T + bproj
    {
        GJobs js;
        js.j[0] = mkjob(O2, 784, 0, 0, Wproj, bproj, nullptr, 1, 0, 0, (float*)d_out, 784, 1.f, 0);
        js.j[1] = js.j[2] = js.j[3] = js.j[0];
        gemm_multi<<<dim3(4, 7, 1), blk, 0, stream>>>(js);
    }
}

// Round 6
// 317.272 us; speedup vs baseline: 1.3302x; 1.3302x over previous
//
#include <hip/hip_runtime.h>
#include <math.h>

#define DIM 512
#define HEADS 8
#define QL 225
#define VS 196
#define BATCH 4
#define EPS_BN 1e-5f

typedef __attribute__((ext_vector_type(8))) short bf16x8;
typedef __attribute__((ext_vector_type(4))) float f32x4;

// ---------------- wave (64-lane) reductions ----------------
__device__ __forceinline__ float waveMax(float v) {
#pragma unroll
    for (int o = 32; o; o >>= 1) v = fmaxf(v, __shfl_xor(v, o, 64));
    return v;
}
__device__ __forceinline__ float waveSum(float v) {
#pragma unroll
    for (int o = 32; o; o >>= 1) v += __shfl_xor(v, o, 64);
    return v;
}

// ---------------- fp32 -> bf16 pack helpers ----------------
__device__ __forceinline__ unsigned cvt_pk_bf16(float lo, float hi) {
    unsigned r;
    asm("v_cvt_pk_bf16_f32 %0, %1, %2" : "=v"(r) : "v"(lo), "v"(hi));
    return r;
}
__device__ __forceinline__ uint4 ld_cvt8(const float* p) {
    float4 x = *(const float4*)p;
    float4 y = *(const float4*)(p + 4);
    uint4 r;
    r.x = cvt_pk_bf16(x.x, x.y);
    r.y = cvt_pk_bf16(x.z, x.w);
    r.z = cvt_pk_bf16(y.x, y.y);
    r.w = cvt_pk_bf16(y.z, y.w);
    return r;
}

// ---------------- multi-job bf16-MFMA GEMM (N=K=512): Out = scale*A@W^T (+bias)(relu)(+Add) ----
// Tile 64x64, BK=64, 4 waves in 2x2 (each 32x32 = 2x2 frags of 16x16x32).
// LDS 18 KB -> 8 blocks/CU for latency hiding. template<LAYER> for rocprof visibility.
struct GJob {
    const float* A; const float* W; const float* bias; const float* Add; float* Out;
    long aBS, aOff, addBS, addOff;
    int aRows, addRows, M, relu;
    float scale; int pad0, pad1, pad2;
};
struct GJobs { GJob j[4]; };

template<int LAYER>
__global__ __launch_bounds__(256) void gemm_multi(GJobs jobs) {
    const GJob J = jobs.j[blockIdx.z];
    const int bm = blockIdx.y * 64, bn = blockIdx.x * 64;
    if (bm >= J.M) return;
    __shared__ __align__(16) ushort As[64][72];
    __shared__ __align__(16) ushort Bs[64][72];
    const int tid = threadIdx.x;
    const int srow = tid >> 2, skq = tid & 3;   // staging: row 0..63, 16-k chunk
    const float* ap = nullptr;
    {
        int m = bm + srow;
        if (m < J.M) { int bb = m / J.aRows; int r = m - bb * J.aRows;
                       ap = J.A + bb * J.aBS + J.aOff + (long)r * 512 + skq * 16; }
    }
    const float* bp = J.W + (long)(bn + srow) * 512 + skq * 16;

    const int lane = tid & 63, wid = tid >> 6;
    const int wr = wid >> 1, wc = wid & 1;      // 2x2 wave grid of 32x32 tiles
    const int lr = lane & 15, kg = lane >> 4;

    f32x4 acc[2][2] = {};

    for (int kt = 0; kt < 512; kt += 64) {
        uint4 a01 = {0u,0u,0u,0u}, a23 = {0u,0u,0u,0u};
        if (ap) { a01 = ld_cvt8(ap + kt); a23 = ld_cvt8(ap + kt + 8); }
        uint4 b01 = ld_cvt8(bp + kt), b23 = ld_cvt8(bp + kt + 8);
        __syncthreads();
        *(uint4*)&As[srow][skq * 16]     = a01;
        *(uint4*)&As[srow][skq * 16 + 8] = a23;
        *(uint4*)&Bs[srow][skq * 16]     = b01;
        *(uint4*)&Bs[srow][skq * 16 + 8] = b23;
        __syncthreads();
        bf16x8 a[2][2], bb[2][2];
#pragma unroll
        for (int i = 0; i < 2; i++)
#pragma unroll
            for (int kf = 0; kf < 2; kf++)
                a[i][kf] = *(const bf16x8*)&As[wr * 32 + i * 16 + lr][kf * 32 + kg * 8];
#pragma unroll
        for (int j = 0; j < 2; j++)
#pragma unroll
            for (int kf = 0; kf < 2; kf++)
                bb[j][kf] = *(const bf16x8*)&Bs[wc * 32 + j * 16 + lr][kf * 32 + kg * 8];
#pragma unroll
        for (int i = 0; i < 2; i++)
#pragma unroll
            for (int j = 0; j < 2; j++) {
                acc[i][j] = __builtin_amdgcn_mfma_f32_16x16x32_bf16(a[i][0], bb[j][0], acc[i][j], 0, 0, 0);
                acc[i][j] = __builtin_amdgcn_mfma_f32_16x16x32_bf16(a[i][1], bb[j][1], acc[i][j], 0, 0, 0);
            }
    }

    // C/D layout: col = lane&15, row = (lane>>4)*4 + reg
#pragma unroll
    for (int i = 0; i < 2; i++) {
#pragma unroll
        for (int r = 0; r < 4; r++) {
            int m = bm + wr * 32 + i * 16 + kg * 4 + r;
            if (m >= J.M) continue;
            const float* addrow = nullptr;
            if (J.Add) {
                int bb2 = m / J.addRows; int rr = m - bb2 * J.addRows;
                addrow = J.Add + bb2 * J.addBS + J.addOff + (long)rr * 512;
            }
            float* orow = J.Out + (long)m * 512;
#pragma unroll
            for (int j = 0; j < 2; j++) {
                int n = bn + wc * 32 + j * 16 + lr;
                float v = acc[i][j][r] * J.scale;
                if (J.bias) v += J.bias[n];
                if (J.relu) v = fmaxf(v, 0.f);
                if (addrow) v += addrow[n];
                orow[n] = v;
            }
        }
    }
}

// ---------------- attention 1: P[b,h,n,q] = softmax_n( q[b,q,:]·k[b,n,:] ) (transposed store) ----
__global__ __launch_bounds__(256) void attn1_kernel(const float* __restrict__ qs,
                                                    const float* __restrict__ ks,
                                                    float* __restrict__ P) {
    int bid = blockIdx.x;
    int qi = bid % QL;
    int h = (bid / QL) % HEADS;
    int b = bid / (QL * HEADS);
    __shared__ __align__(16) float qrow[64];
    __shared__ float redm[4], reds[4];
    int tid = threadIdx.x;
    if (tid < 64) qrow[tid] = qs[((long)(b * QL + qi)) * DIM + h * 64 + tid];
    __syncthreads();
    float s = -1e30f;
    if (tid < VS) {
        const float4* kr4 = (const float4*)(ks + ((long)(b * VS + tid)) * DIM + h * 64);
        const float4* q4 = (const float4*)qrow;
        float acc = 0.f;
#pragma unroll
        for (int i = 0; i < 16; i++) {
            float4 kv = kr4[i], qv = q4[i];
            acc += qv.x * kv.x + qv.y * kv.y + qv.z * kv.z + qv.w * kv.w;
        }
        s = acc;
    }
    float wm = waveMax(s);
    if ((tid & 63) == 0) redm[tid >> 6] = wm;
    __syncthreads();
    float m = fmaxf(fmaxf(redm[0], redm[1]), fmaxf(redm[2], redm[3]));
    float e = (tid < VS) ? expf(s - m) : 0.f;
    float ws = waveSum(e);
    if ((tid & 63) == 0) reds[tid >> 6] = ws;
    __syncthreads();
    float tot = reds[0] + reds[1] + reds[2] + reds[3];
    if (tid < VS) P[(((long)(b * HEADS + h)) * VS + tid) * QL + qi] = e / tot;
}

// ---------------- fused: h = P*v -> dwconv1+bn1+relu -> dwconv2+bn2+relu -> mean over n ----
// v3: 4 planes per block (one per wave). Lane owns 4 columns (c0=4*lane), rolling
// 3-row register windows for h and g, shfl only for the 2 edge columns per level.
#define CSTEP4(N, HA,HAl,HAr, HB,HBl,HBr, HC,HCl,HCr, GA,GAl,GAr, GB,GBl,GBr, GC,GCl,GCr)      \
{                                                                                              \
    float4 pv = make_float4(0.f, 0.f, 0.f, 0.f);                                               \
    if ((N) < VS) {                                                                            \
        float vn = vcolw[wave][(N)];                                                           \
        const float* rp = Pp + (long)(N) * QL;                                                 \
        pv.x = rp[off0] * vn * mk0;                                                            \
        pv.y = rp[off1] * vn * mk1;                                                            \
        pv.z = rp[off2] * vn * mk2;                                                            \
        pv.w = rp[off3] * vn * mk3;                                                            \
    }                                                                                          \
    HC = pv;                                                                                   \
    HCl = __shfl_up(pv.w, 1, 64); if (lane == 0) HCl = 0.f;                                    \
    HCr = __shfl_down(pv.x, 1, 64);                                                            \
    float4 g = make_float4(0.f, 0.f, 0.f, 0.f);                                                \
    if ((N) >= 1 && (N) <= VS) {                                                               \
        g.x = w1s[0]*HAl  + w1s[1]*HA.x + w1s[2]*HA.y                                          \
            + w1s[3]*HBl  + w1s[4]*HB.x + w1s[5]*HB.y                                          \
            + w1s[6]*HCl  + w1s[7]*HC.x + w1s[8]*HC.y;                                         \
        g.y = w1s[0]*HA.x + w1s[1]*HA.y + w1s[2]*HA.z                                          \
            + w1s[3]*HB.x + w1s[4]*HB.y + w1s[5]*HB.z                                          \
            + w1s[6]*HC.x + w1s[7]*HC.y + w1s[8]*HC.z;                                         \
        g.z = w1s[0]*HA.y + w1s[1]*HA.z + w1s[2]*HA.w                                          \
            + w1s[3]*HB.y + w1s[4]*HB.z + w1s[5]*HB.w                                          \
            + w1s[6]*HC.y + w1s[7]*HC.z + w1s[8]*HC.w;                                         \
        g.w = w1s[0]*HA.z + w1s[1]*HA.w + w1s[2]*HAr                                           \
            + w1s[3]*HB.z + w1s[4]*HB.w + w1s[5]*HBr                                           \
            + w1s[6]*HC.z + w1s[7]*HC.w + w1s[8]*HCr;                                          \
        g.x = fmaxf(g.x * s1 + b1v, 0.f) * mk0;                                                \
        g.y = fmaxf(g.y * s1 + b1v, 0.f) * mk1;                                                \
        g.z = fmaxf(g.z * s1 + b1v, 0.f) * mk2;                                                \
        g.w = fmaxf(g.w * s1 + b1v, 0.f) * mk3;                                                \
    }                                                                                          \
    GC = g;                                                                                    \
    GCl = __shfl_up(g.w, 1, 64); if (lane == 0) GCl = 0.f;                                     \
    GCr = __shfl_down(g.x, 1, 64);                                                             \
    if ((N) >= 2) {                                                                            \
        float t0 = w2s[0]*GAl  + w2s[1]*GA.x + w2s[2]*GA.y                                     \
                 + w2s[3]*GBl  + w2s[4]*GB.x + w2s[5]*GB.y                                     \
                 + w2s[6]*GCl  + w2s[7]*GC.x + w2s[8]*GC.y;                                    \
        float t1 = w2s[0]*GA.x + w2s[1]*GA.y + w2s[2]*GA.z                                     \
                 + w2s[3]*GB.x + w2s[4]*GB.y + w2s[5]*GB.z                                     \
                 + w2s[6]*GC.x + w2s[7]*GC.y + w2s[8]*GC.z;                                    \
        float t2 = w2s[0]*GA.y + w2s[1]*GA.z + w2s[2]*GA.w                                     \
                 + w2s[3]*GB.y + w2s[4]*GB.z + w2s[5]*GB.w                                     \
                 + w2s[6]*GC.y + w2s[7]*GC.z + w2s[8]*GC.w;                                    \
        float t3 = w2s[0]*GA.z + w2s[1]*GA.w + w2s[2]*GAr                                      \
                 + w2s[3]*GB.z + w2s[4]*GB.w + w2s[5]*GBr                                      \
                 + w2s[6]*GC.z + w2s[7]*GC.w + w2s[8]*GCr;                                     \
        csum.x += fmaxf(t0 * s2 + b2v, 0.f);                                                   \
        csum.y += fmaxf(t1 * s2 + b2v, 0.f);                                                   \
        csum.z += fmaxf(t2 * s2 + b2v, 0.f);                                                   \
        csum.w += fmaxf(t3 * s2 + b2v, 0.f);                                                   \
    }                                                                                          \
}

__global__ __launch_bounds__(256) void conv_fuse_kernel(
    const float* __restrict__ P, const float* __restrict__ vs,
    const float* __restrict__ dw1, const float* __restrict__ dw2,
    const float* __restrict__ bn1g, const float* __restrict__ bn1b,
    const float* __restrict__ bn1m, const float* __restrict__ bn1v,
    const float* __restrict__ bn2g, const float* __restrict__ bn2b,
    const float* __restrict__ bn2m, const float* __restrict__ bn2v,
    float* __restrict__ m2) {
    int bc = blockIdx.x;            // 512 blocks: b = bc>>7, channel group = (bc&127)*4
    int b = bc >> 7;
    int cq = (bc & 127) * 4;
    int tid = threadIdx.x;
    int wave = tid >> 6, lane = tid & 63;
    int c = cq + wave;              // this wave's channel (same head for all 4 waves)
    int h = c >> 6;
    __shared__ float vcolw[4][200];
    // cooperative, semi-coalesced vcol load: thread t -> (channel t&3, n = t>>2 + 64p)
#pragma unroll
    for (int p = 0; p < 4; p++) {
        int n = (tid >> 2) + (p << 6);
        if (n < VS) vcolw[tid & 3][n] = vs[((long)(b * VS + n)) * DIM + cq + (tid & 3)];
    }
    float w1s[9], w2s[9];
#pragma unroll
    for (int i = 0; i < 9; i++) { w1s[i] = dw1[c * 9 + i]; w2s[i] = dw2[c * 9 + i]; }
    float s1 = bn1g[c] * rsqrtf(bn1v[c] + EPS_BN);
    float b1v = bn1b[c] - bn1m[c] * s1;
    float s2 = bn2g[c] * rsqrtf(bn2v[c] + EPS_BN);
    float b2v = bn2b[c] - bn2m[c] * s2;
    const float* Pp = P + ((long)(b * HEADS + h)) * VS * QL;
    // lane owns columns c0..c0+3
    int c0 = lane * 4;
    float mk0 = (c0 + 0 < QL) ? 1.f : 0.f;
    float mk1 = (c0 + 1 < QL) ? 1.f : 0.f;
    float mk2 = (c0 + 2 < QL) ? 1.f : 0.f;
    float mk3 = (c0 + 3 < QL) ? 1.f : 0.f;
    int off0 = min(c0 + 0, QL - 1), off1 = min(c0 + 1, QL - 1);
    int off2 = min(c0 + 2, QL - 1), off3 = min(c0 + 3, QL - 1);
    __syncthreads();
    float4 hA = make_float4(0,0,0,0), hB = hA, hC = hA;
    float hAl = 0, hAr = 0, hBl = 0, hBr = 0, hCl = 0, hCr = 0;
    float4 gA = make_float4(0,0,0,0), gB = gA, gC = gA;
    float gAl = 0, gAr = 0, gBl = 0, gBr = 0, gCl = 0, gCr = 0;
    float4 csum = make_float4(0,0,0,0);
    for (int nb = 0; nb < 198; nb += 3) {
        CSTEP4(nb,     hA,hAl,hAr, hB,hBl,hBr, hC,hCl,hCr, gA,gAl,gAr, gB,gBl,gBr, gC,gCl,gCr)
        CSTEP4(nb + 1, hB,hBl,hBr, hC,hCl,hCr, hA,hAl,hAr, gB,gBl,gBr, gC,gCl,gCr, gA,gAl,gAr)
        CSTEP4(nb + 2, hC,hCl,hCr, hA,hAl,hAr, hB,hBl,hBr, gC,gCl,gCr, gA,gAl,gAr, gB,gBl,gBr)
    }
    const float inv = 1.f / (float)VS;
    if (c0 + 0 < QL) m2[((long)(b * QL + c0 + 0)) * DIM + c] = csum.x * inv;
    if (c0 + 1 < QL) m2[((long)(b * QL + c0 + 1)) * DIM + c] = csum.y * inv;
    if (c0 + 2 < QL) m2[((long)(b * QL + c0 + 2)) * DIM + c] = csum.z * inv;
    if (c0 + 3 < QL) m2[((long)(b * QL + c0 + 3)) * DIM + c] = csum.w * inv;
}

// ---------------- attention 2: O[b,n,:] = Qm[b,n,:] + softmax_q(Qm·Km/sqrt(512)) @ Vm ----
__global__ __launch_bounds__(256) void attn2_kernel(const float* __restrict__ Qm,
                                                    const float* __restrict__ Km,
                                                    const float* __restrict__ Vm,
                                                    float* __restrict__ O) {
    int bid = blockIdx.x;
    int n = bid % VS;
    int h = (bid / VS) % HEADS;
    int b = bid / (VS * HEADS);
    __shared__ __align__(16) float qrow[64];
    __shared__ float av[QL];
    __shared__ __align__(16) float4 red4[16][16];
    __shared__ float redm[4], reds[4];
    int tid = threadIdx.x;
    if (tid < 64) qrow[tid] = Qm[((long)(b * VS + n)) * DIM + h * 64 + tid];
    __syncthreads();
    float s = -1e30f;
    if (tid < QL) {
        const float4* kr4 = (const float4*)(Km + ((long)(b * QL + tid)) * DIM + h * 64);
        const float4* q4 = (const float4*)qrow;
        float acc = 0.f;
#pragma unroll
        for (int i = 0; i < 16; i++) {
            float4 kv = kr4[i], qv = q4[i];
            acc += qv.x * kv.x + qv.y * kv.y + qv.z * kv.z + qv.w * kv.w;
        }
        s = acc * 0.044194173824159216f; // 1/sqrt(512)
    }
    float wm = waveMax(s);
    if ((tid & 63) == 0) redm[tid >> 6] = wm;
    __syncthreads();
    float m = fmaxf(fmaxf(redm[0], redm[1]), fmaxf(redm[2], redm[3]));
    float e = (tid < QL) ? expf(s - m) : 0.f;
    float ws = waveSum(e);
    if ((tid & 63) == 0) reds[tid >> 6] = ws;
    __syncthreads();
    float tot = reds[0] + reds[1] + reds[2] + reds[3];
    if (tid < QL) av[tid] = e / tot;
    __syncthreads();
    // PV: thread = (qp = tid>>4, dq = tid&15); float4 over d
    int qp = tid >> 4, dq = tid & 15;
    float4 acc4 = make_float4(0, 0, 0, 0);
    for (int it = 0; it < 15; it++) {
        int qq = it * 16 + qp;
        if (qq < QL) {
            float a = av[qq];
            float4 v4 = *(const float4*)(Vm + ((long)(b * QL + qq)) * DIM + h * 64 + dq * 4);
            acc4.x += a * v4.x; acc4.y += a * v4.y; acc4.z += a * v4.z; acc4.w += a * v4.w;
        }
    }
    red4[qp][dq] = acc4;
    __syncthreads();
#pragma unroll
    for (int st = 8; st >= 1; st >>= 1) {
        if (qp < st) {
            float4 o = red4[qp + st][dq];
            acc4.x += o.x; acc4.y += o.y; acc4.z += o.z; acc4.w += o.w;
            red4[qp][dq] = acc4;
        }
        __syncthreads();
    }
    if (tid < 16) {
        float4 r = red4[0][tid];
        float4 qv = ((const float4*)qrow)[tid];
        float4 o = make_float4(qv.x + r.x, qv.y + r.y, qv.z + r.z, qv.w + r.w);
        *(float4*)(O + ((long)(b * VS + n)) * DIM + h * 64 + tid * 4) = o;
    }
}

static inline GJob mkjob(const float* A, int aRows, long aBS, long aOff,
                         const float* W, const float* bias,
                         const float* Add, int addRows, long addBS, long addOff,
                         float* Out, int M, float scale, int relu) {
    GJob j;
    j.A = A; j.W = W; j.bias = bias; j.Add = Add; j.Out = Out;
    j.aBS = aBS; j.aOff = aOff; j.addBS = addBS; j.addOff = addOff;
    j.aRows = aRows; j.addRows = addRows; j.M = M; j.relu = relu;
    j.scale = scale; j.pad0 = j.pad1 = j.pad2 = 0;
    return j;
}

extern "C" void kernel_launch(void* const* d_in, const int* in_sizes, int n_in,
                              void* d_out, int out_size, void* d_ws, size_t ws_size,
                              hipStream_t stream) {
    const float* x     = (const float*)d_in[0];
    const float* Wq    = (const float*)d_in[1];
    const float* Wk    = (const float*)d_in[2];
    const float* Wv    = (const float*)d_in[3];
    const float* Wproj = (const float*)d_in[4];
    const float* bproj = (const float*)d_in[5];
    const float* dw1   = (const float*)d_in[6];
    const float* dw2   = (const float*)d_in[7];
    const float* pw    = (const float*)d_in[8];
    const float* bn1g  = (const float*)d_in[9];
    const float* bn1b  = (const float*)d_in[10];
    const float* bn1m  = (const float*)d_in[11];
    const float* bn1v  = (const float*)d_in[12];
    const float* bn2g  = (const float*)d_in[13];
    const float* bn2b  = (const float*)d_in[14];
    const float* bn2m  = (const float*)d_in[15];
    const float* bn2v  = (const float*)d_in[16];
    const float* mWq   = (const float*)d_in[17];
    const float* mbq   = (const float*)d_in[18];
    const float* mWk   = (const float*)d_in[19];
    const float* mbk   = (const float*)d_in[20];
    const float* mWv   = (const float*)d_in[21];
    const float* mbv   = (const float*)d_in[22];
    const float* mWo   = (const float*)d_in[23];
    const float* mbo   = (const float*)d_in[24];

    float* ws = (float*)d_ws;
    // Overlay (floats):
    //   qs @ 0 (460800) -> m2 -> Km
    //   ks @ 460800 (401408) -> O
    //   vsb @ 862208 (401408) -> O2
    //   P @ 1263616 (1411200) -> [kc @ +0 | Qm @ +460800 | Vm @ +862208]
    float* qs = ws;
    float* ks = ws + 460800;
    float* vsb = ws + 862208;
    float* P  = ws + 1263616;
    float* m2 = ws;
    float* kc = ws + 1263616;
    float* Qm = ws + 1263616 + 460800;
    float* Vm = ws + 1263616 + 460800 + 401408;
    float* Km = ws;
    float* O  = ws + 460800;
    float* O2 = ws + 862208;

    const long xBS = 421L * DIM;
    const long clsOff = 196L * DIM;

    dim3 blk(256);

    // L1: q,k,v projections fused (360 blocks)
    {
        GJobs js;
        js.j[0] = mkjob(x, QL, xBS, clsOff, Wq, nullptr, nullptr, 1, 0, 0, qs, 900, 0.125f, 0);
        js.j[1] = mkjob(x, VS, xBS, 0, Wk, nullptr, nullptr, 1, 0, 0, ks, 784, 1.f, 0);
        js.j[2] = mkjob(x, VS, xBS, 0, Wv, nullptr, nullptr, 1, 0, 0, vsb, 784, 1.f, 0);
        js.j[3] = js.j[0];
        gemm_multi<0><<<dim3(8, 15, 3), blk, 0, stream>>>(js);
    }
    attn1_kernel<<<BATCH * HEADS * QL, blk, 0, stream>>>(qs, ks, P);
    conv_fuse_kernel<<<512, blk, 0, stream>>>(P, vsb, dw1, dw2,
                                              bn1g, bn1b, bn1m, bn1v,
                                              bn2g, bn2b, bn2m, bn2v, m2);
    // L2: kc = cls_cat + m2 @ pw^T  AND  Qm = x_sem @ mWq^T + mbq   (P dead now)
    {
        GJobs js;
        js.j[0] = mkjob(m2, 900, 0, 0, pw, nullptr, x, QL, xBS, clsOff, kc, 900, 1.f, 0);
        js.j[1] = mkjob(x, VS, xBS, 0, mWq, mbq, nullptr, 1, 0, 0, Qm, 784, 1.f, 0);
        js.j[2] = js.j[3] = js.j[0];
        gemm_multi<1><<<dim3(8, 15, 2), blk, 0, stream>>>(js);
    }
    // L3: Km, Vm off kc
    {
        GJobs js;
        js.j[0] = mkjob(kc, 900, 0, 0, mWk, mbk, nullptr, 1, 0, 0, Km, 900, 1.f, 0);
        js.j[1] = mkjob(kc, 900, 0, 0, mWv, mbv, nullptr, 1, 0, 0, Vm, 900, 1.f, 0);
        js.j[2] = js.j[3] = js.j[0];
        gemm_multi<2><<<dim3(8, 15, 2), blk, 0, stream>>>(js);
    }
    attn2_kernel<<<BATCH * HEADS * VS, blk, 0, stream>>>(Qm, Km, Vm, O);
    // L4: O2 = O + relu(O @ mWo^T + mbo)
    {
        GJobs js;
        js.j[0] = mkjob(O, 784, 0, 0, mWo, mbo, O, 784, 0, 0, O2, 784, 1.f, 1);
        js.j[1] = js.j[2] = js.j[3] = js.j[0];
        gemm_multi<3><<<dim3(8, 13, 1), blk, 0, stream>>>(js);
    }
    // L5: out = O2 @ Wproj^T + bproj
    {
        GJobs js;
        js.j[0] = mkjob(O2, 784, 0, 0, Wproj, bproj, nullptr, 1, 0, 0, (float*)d_out, 784, 1.f, 0);
        js.j[1] = js.j[2] = js.j[3] = js.j[0];
        gemm_multi<4><<<dim3(8, 13, 1), blk, 0, stream>>>(js);
    }
}